// Round 4
// baseline (76.833 us; speedup 1.0000x reference)
//
#include <hip/hip_runtime.h>
#include <math.h>

// HSTU positional encoder:
//   out[t,:] = emb[t,:] * sqrt(D) + pos_weight[pos(t),:]
//   pos(t) = clip( min(len[seg],P-1) - (t - offset[seg]), 0, P-1 )
// D = 512 (128 f32x4/row). Memory-bound.
//
// R4: XCD-pinned position-locality decomposition. Work unit = "strip"
// (seq b, chunk c) of CT=32 tokens. XCD x (= blockIdx.x % 8, empirical
// round-robin dispatch) owns chunk range [x*C8, (x+1)*C8). Sequence
// lengths are near-equal here, so equal-c strips across sequences read
// the SAME ~32 wt rows -> per-XCD wt working set ~2 MB < 4 MB L2, each
// table row crosses the fabric once instead of 16x. emb/out streaming is
// untouched (contiguous per strip). Mapping is a perf heuristic only —
// correctness never depends on which XCD runs a block.

constexpr int D_DIM = 512;
constexpr int D4 = D_DIM / 4;    // 128 f32x4 per row
constexpr int CT = 32;           // tokens per strip
constexpr int MAXB = 16;         // reference B; generic fallback below
constexpr int NXCD = 8;

typedef float f32x4 __attribute__((ext_vector_type(4)));

__global__ __launch_bounds__(256, 8)
void hstu_pos_enc_xcd(const int* __restrict__ seq_lengths,
                      const int* __restrict__ seq_offsets,
                      const float* __restrict__ emb,
                      const float* __restrict__ wt,
                      float* __restrict__ out,
                      int nseq, int maxpos, float alpha)
{
    const f32x4* __restrict__ emb4 = reinterpret_cast<const f32x4*>(emb);
    const f32x4* __restrict__ wt4  = reinterpret_cast<const f32x4*>(wt);
    f32x4* __restrict__ out4       = reinterpret_cast<f32x4*>(out);

    // Per-sequence tables in registers (compile-time indices, uniform loads).
    int offs[MAXB], lens[MAXB], highs[MAXB], nck[MAXB];
    int MC = 1;
#pragma unroll
    for (int b = 0; b < MAXB; ++b) {
        lens[b]  = (b < nseq) ? seq_lengths[b] : 0;
        offs[b]  = (b < nseq) ? seq_offsets[b] : 0;
        highs[b] = min(lens[b], maxpos - 1);
        nck[b]   = (lens[b] + CT - 1) / CT;
        MC = max(MC, nck[b]);
    }
    int C8 = (MC + NXCD - 1) / NXCD;        // chunks per XCD
    int x  = (int)blockIdx.x % NXCD;        // XCD id (heuristic)
    int g  = (int)blockIdx.x / NXCD;        // block index within XCD
    int blocksPerXcd = (int)gridDim.x / NXCD;
    int stripsPerXcd = MAXB * C8;

    for (int s = g; s < stripsPerXcd; s += blocksPerXcd) {
        int b  = s & (MAXB - 1);            // sequence
        int cl = s >> 4;                    // local chunk (MAXB==16)
        int c  = x * C8 + cl;               // global chunk of sequence b
        if (c >= nck[b]) continue;

        int t0     = offs[b] + c * CT;                  // first token
        int nval   = min(CT * D4, (offs[b] + lens[b] - t0) * D4);
        int ebase  = t0 * D4;
        int posTop = highs[b] - c * CT;                 // pos of local tok 0

        for (int e = threadIdx.x; e < nval; e += 256) {
            // e>>7 is wave-uniform (64 consecutive lanes = half a row)
            int lt  = __builtin_amdgcn_readfirstlane(e >> 7);
            int c4  = e & (D4 - 1);
            int pos = posTop - lt;
            pos = min(max(pos, 0), maxpos - 1);

            f32x4 ev = __builtin_nontemporal_load(&emb4[ebase + e]);
            f32x4 wv = wt4[pos * D4 + c4];   // L2-resident window
            f32x4 o;
            o.x = fmaf(ev.x, alpha, wv.x);
            o.y = fmaf(ev.y, alpha, wv.y);
            o.z = fmaf(ev.z, alpha, wv.z);
            o.w = fmaf(ev.w, alpha, wv.w);
            __builtin_nontemporal_store(o, &out4[ebase + e]);
        }
    }
}

// Generic fallback for nseq > MAXB or D != 512-style layouts (not hit here).
__global__ void hstu_pos_enc_generic(const int* __restrict__ seq_lengths,
                                     const int* __restrict__ seq_offsets,
                                     const float* __restrict__ emb,
                                     const float* __restrict__ wt,
                                     float* __restrict__ out,
                                     int nelem4, int nseq, int maxpos,
                                     float alpha)
{
    const f32x4* __restrict__ emb4 = reinterpret_cast<const f32x4*>(emb);
    const f32x4* __restrict__ wt4  = reinterpret_cast<const f32x4*>(wt);
    f32x4* __restrict__ out4       = reinterpret_cast<f32x4*>(out);

    int stride = gridDim.x * blockDim.x;
    for (int idx = blockIdx.x * blockDim.x + threadIdx.x;
         idx < nelem4; idx += stride) {
        int tok = idx >> 7;
        int c4  = idx & (D4 - 1);
        int seg = 0;
        for (int b = 1; b < nseq; ++b)
            if (seq_offsets[b] <= tok) seg = b;
        int start = seq_offsets[seg];
        int high  = min(seq_lengths[seg], maxpos - 1);
        int pos   = min(max(high - (tok - start), 0), maxpos - 1);
        f32x4 e = emb4[idx];
        f32x4 w = wt4[pos * D4 + c4];
        f32x4 o;
        o.x = fmaf(e.x, alpha, w.x);
        o.y = fmaf(e.y, alpha, w.y);
        o.z = fmaf(e.z, alpha, w.z);
        o.w = fmaf(e.w, alpha, w.w);
        out4[idx] = o;
    }
}

extern "C" void kernel_launch(void* const* d_in, const int* in_sizes, int n_in,
                              void* d_out, int out_size, void* d_ws, size_t ws_size,
                              hipStream_t stream)
{
    // Inputs (setup_inputs order):
    // 0: max_seq_len scalar, 1: seq_lengths[B], 2: seq_offsets[B+1],
    // 3: seq_embeddings[TOTAL,D] f32, 4: pos_weight[P,D] f32
    const int*   seq_lengths = (const int*)d_in[1];
    const int*   seq_offsets = (const int*)d_in[2];
    const float* emb         = (const float*)d_in[3];
    const float* wt          = (const float*)d_in[4];
    float*       out         = (float*)d_out;

    int B     = in_sizes[1];
    int P     = in_sizes[4] / D_DIM;
    int total = in_sizes[3] / D_DIM;
    float alpha = sqrtf((float)D_DIM);

    if (B <= MAXB) {
        // 2048 blocks x 256 = 8192 waves: exactly fully resident.
        hstu_pos_enc_xcd<<<dim3(2048), dim3(256), 0, stream>>>(
            seq_lengths, seq_offsets, emb, wt, out, B, P, alpha);
    } else {
        int nelem4 = total * D4;
        int grid = (nelem4 + 255) / 256;
        if (grid > 2048) grid = 2048;
        hstu_pos_enc_generic<<<dim3(grid), dim3(256), 0, stream>>>(
            seq_lengths, seq_offsets, emb, wt, out, nelem4, B, P, alpha);
    }
}

// Round 5
// 54.924 us; speedup vs baseline: 1.3989x; 1.3989x over previous
//
#include <hip/hip_runtime.h>
#include <math.h>

// HSTU positional encoder:
//   out[t,:] = emb[t,:] * sqrt(D) + pos_weight[clip(pos),:]
//   pos(t) = min(len[b],P-1) - (t - off[b]), clipped to [0, P-1]
//
// R5: position-window decomposition. Block w owns positions
// [w*CT, w*CT+CT). It stages those CT wt rows into LDS ONCE, then applies
// them to the matching CT-token strip of ALL 16 sequences (positions of
// the 16 ragged sequences overlap almost completely). wt is read from
// the memory path exactly once total (~8 MB instead of 134 MB of
// LLC-served gathers) — the R1/R3 plateau was combined-path throughput
// (262 MB HBM + 134 MB LLC wt ≈ 6.6 TB/s ≈ copy ceiling), so removing
// the wt stream converts directly to time.
// Plain stores (R4 showed nt stores + scattered strips => 1.5x WRITE).

constexpr int D_DIM = 512;
constexpr int D4 = D_DIM / 4;    // 128 f32x4 per row
constexpr int CT = 4;            // positions (wt rows) per window/block
constexpr int MAXB = 16;

typedef float f32x4 __attribute__((ext_vector_type(4)));

__global__ __launch_bounds__(512, 4)
void hstu_pos_enc_win(const int* __restrict__ seq_lengths,
                      const int* __restrict__ seq_offsets,
                      const float* __restrict__ emb,
                      const float* __restrict__ wt,
                      float* __restrict__ out,
                      int nseq, int maxpos, float alpha)
{
    __shared__ f32x4 lds[CT * D4];          // 4 rows x 2 KB = 8 KB

    const f32x4* __restrict__ emb4 = reinterpret_cast<const f32x4*>(emb);
    const f32x4* __restrict__ wt4  = reinterpret_cast<const f32x4*>(wt);
    f32x4* __restrict__ out4       = reinterpret_cast<f32x4*>(out);

    const int p0 = (int)blockIdx.x * CT;    // first position of this window

    // Per-sequence token range whose (clipped) position falls in the window.
    // All scalar math, compile-time indices -> registers/SALU.
    int phi[MAXB], cnt[MAXB], t00[MAXB];
    int any = 0;
#pragma unroll
    for (int b = 0; b < MAXB; ++b) {
        int len  = (b < nseq) ? seq_lengths[b] : 0;
        int off  = (b < nseq) ? seq_offsets[b] : 0;
        int high = min(len, maxpos - 1);
        int pmin = high - len + 1;          // lowest unclipped position
        int lo   = (p0 == 0) ? pmin : max(p0, pmin);  // w0 takes clipped tail
        int hi   = min(p0 + CT - 1, high);
        phi[b] = hi;
        cnt[b] = hi - lo + 1;               // <=0 -> no tokens here
        t00[b] = off + high - hi;           // token with j==0 (pos==hi)
        any |= (hi >= lo) ? 1 : 0;
    }
    if (!any) return;                       // window above all sequences

    // Stage wt rows [p0, p0+CT) once (clamped to table size).
    int nstage = min(CT, maxpos - p0) * D4;
    for (int s = (int)threadIdx.x; s < nstage; s += 512)
        lds[s] = wt4[p0 * D4 + s];
    __syncthreads();

    const int lt = __builtin_amdgcn_readfirstlane((int)threadIdx.x >> 7);
    const int c4 = (int)threadIdx.x & (D4 - 1);

#pragma unroll
    for (int b = 0; b < MAXB; ++b) {
        int count = cnt[b];
        // count <= CT except (w==0 && len > maxpos-1): clipped tail, all row 0.
        for (int j0 = 0; j0 < count; j0 += CT) {
            int j = j0 + lt;
            if (j < count) {
                int t   = t00[b] + j;
                int p   = phi[b] - j;               // unclipped position
                int row = max(p, p0) - p0;          // LDS row (handles clip)
                f32x4 ev = emb4[t * D4 + c4];
                f32x4 wv = lds[row * D4 + c4];
                f32x4 o;
                o.x = fmaf(ev.x, alpha, wv.x);
                o.y = fmaf(ev.y, alpha, wv.y);
                o.z = fmaf(ev.z, alpha, wv.z);
                o.w = fmaf(ev.w, alpha, wv.w);
                out4[t * D4 + c4] = o;
            }
        }
    }
}

// Generic fallback for nseq > MAXB (not hit in this bench).
__global__ void hstu_pos_enc_generic(const int* __restrict__ seq_lengths,
                                     const int* __restrict__ seq_offsets,
                                     const float* __restrict__ emb,
                                     const float* __restrict__ wt,
                                     float* __restrict__ out,
                                     int nelem4, int nseq, int maxpos,
                                     float alpha)
{
    const f32x4* __restrict__ emb4 = reinterpret_cast<const f32x4*>(emb);
    const f32x4* __restrict__ wt4  = reinterpret_cast<const f32x4*>(wt);
    f32x4* __restrict__ out4       = reinterpret_cast<f32x4*>(out);

    int stride = gridDim.x * blockDim.x;
    for (int idx = blockIdx.x * blockDim.x + threadIdx.x;
         idx < nelem4; idx += stride) {
        int tok = idx >> 7;
        int c4  = idx & (D4 - 1);
        int seg = 0;
        for (int b = 1; b < nseq; ++b)
            if (seq_offsets[b] <= tok) seg = b;
        int start = seq_offsets[seg];
        int high  = min(seq_lengths[seg], maxpos - 1);
        int pos   = min(max(high - (tok - start), 0), maxpos - 1);
        f32x4 e = emb4[idx];
        f32x4 w = wt4[pos * D4 + c4];
        f32x4 o;
        o.x = fmaf(e.x, alpha, w.x);
        o.y = fmaf(e.y, alpha, w.y);
        o.z = fmaf(e.z, alpha, w.z);
        o.w = fmaf(e.w, alpha, w.w);
        out4[idx] = o;
    }
}

extern "C" void kernel_launch(void* const* d_in, const int* in_sizes, int n_in,
                              void* d_out, int out_size, void* d_ws, size_t ws_size,
                              hipStream_t stream)
{
    // Inputs (setup_inputs order):
    // 0: max_seq_len scalar, 1: seq_lengths[B], 2: seq_offsets[B+1],
    // 3: seq_embeddings[TOTAL,D] f32, 4: pos_weight[P,D] f32
    const int*   seq_lengths = (const int*)d_in[1];
    const int*   seq_offsets = (const int*)d_in[2];
    const float* emb         = (const float*)d_in[3];
    const float* wt          = (const float*)d_in[4];
    float*       out         = (float*)d_out;

    int B     = in_sizes[1];
    int P     = in_sizes[4] / D_DIM;
    int total = in_sizes[3] / D_DIM;
    float alpha = sqrtf((float)D_DIM);

    if (B <= MAXB) {
        int nwin = (P + CT - 1) / CT;       // windows cover the whole table;
        hstu_pos_enc_win<<<dim3(nwin), dim3(512), 0, stream>>>(
            seq_lengths, seq_offsets, emb, wt, out, B, P, alpha);
    } else {
        int nelem4 = total * D4;
        int grid = (nelem4 + 255) / 256;
        if (grid > 2048) grid = 2048;
        hstu_pos_enc_generic<<<dim3(grid), dim3(256), 0, stream>>>(
            seq_lengths, seq_offsets, emb, wt, out, nelem4, B, P, alpha);
    }
}